// Round 5
// baseline (4915.776 us; speedup 1.0000x reference)
//
#include <hip/hip_runtime.h>
#include <math.h>

#define BB   64      // batch
#define TT_  1024    // sequence length
#define UU   512     // hidden units
#define VV   256     // vocab
#define EE   256     // embedding dim
#define TC   64      // time chunk

typedef unsigned long long u64;

__device__ __forceinline__ float tanh_fast(float x) {
    // tanh(x) = 1 - 2/(e^{2x}+1); abs err ~1e-6 (validated: absmax 6e-5 end-to-end)
    float e = __expf(x + x);
    return 1.f - 2.f * __builtin_amdgcn_rcpf(e + 1.f);
}

// ---------------- E2 = emb @ Wx + b : [256, 512] ----------------
__global__ __launch_bounds__(512) void e2_kernel(
    const float* __restrict__ emb, const float* __restrict__ Wx,
    const float* __restrict__ bias, float* __restrict__ E2)
{
    const int v = blockIdx.x;
    const int u = threadIdx.x;
    float acc = bias[u];
    const float* er = emb + v * EE;
    #pragma unroll 8
    for (int e = 0; e < EE; ++e)
        acc = fmaf(er[e], Wx[e * UU + u], acc);
    E2[v * UU + u] = acc;
}

// ---------------- fused recurrence + logits, push-partials dataflow ----------------
// 256 blocks, CONSECUTIVE grouping: bg = bid>>3 (2 batches), j = bid&7 (k- and
// unit-slice [64j,64j+64)). 512 threads, 1 block/CU (launch_bounds(512,2)) -> all
// 256 resident, spin-wait is deadlock-free.
// Producer role: thread (bp=tid>>8, idx=tid&255) computes partials for global
// units {2idx,2idx+1} of batch b0+bp from its OWN h slice (VGPR Wh columns),
// pushes (tag,val) u64 pairs to pbuf[par][bg][dst][src=j][b][u].
// Collector role: slot=(tid>>6)*16+(lane>>2) -> (bc,uc); sub=lane&3 polls srcs
// {2sub,2sub+1}, alternating sc0(volatile)/sc1(agent) scopes; shfl-reduce x2,
// tanh, write hL. Logits for step s-1 fused into the same k-loop (same h regs).
__global__ __launch_bounds__(512, 2) void rnn_chunk_kernel(
    const int* __restrict__ toks, const float* __restrict__ E2,
    const float* __restrict__ Wh, const float* __restrict__ Wd,
    const float* __restrict__ bd,
    u64* pbuf,            // [2][32][8 dst][8 src][2 b][64 u] (tag,val) pairs, 4 MB
    float* hcar,          // [BB][UU] carry between dispatches
    float* out, int t0)
{
    __shared__ float hL[2][2][64];    // [parity][b][u-local]
    __shared__ int   stok[2][TC];

    const int bid  = blockIdx.x;
    const int bg   = bid >> 3;
    const int j    = bid & 7;
    const int tid  = threadIdx.x;
    const int lane = tid & 63;
    const int w    = tid >> 6;
    const int b0   = bg * 2;

    // producer role
    const int bp     = tid >> 8;        // 0/1
    const int idx    = tid & 255;       // unit-pair index; global units {2idx,2idx+1}
    const int dstblk = idx >> 5;
    // collector role
    const int slot = w * 16 + (lane >> 2);   // 0..127
    const int sub  = lane & 3;               // polls srcs {2sub, 2sub+1}
    const int bc   = slot >> 6;
    const int uc   = slot & 63;

    // ---- weights into VGPRs (once per dispatch) ----
    float2 whp[64];                     // Wh[64j+k][2idx .. 2idx+1]
    const float2* Wh2 = (const float2*)Wh;
    #pragma unroll
    for (int k = 0; k < 64; ++k)
        whp[k] = Wh2[(j * 64 + k) * (UU / 2) + idx];
    float wdreg[64];                    // Wd[64j+u][idx]
    #pragma unroll
    for (int u = 0; u < 64; ++u)
        wdreg[u] = Wd[(j * 64 + u) * VV + idx];
    const float bdv = (j == 0) ? bd[idx] : 0.f;

    if (tid < 128)
        stok[tid >> 6][tid & 63] = toks[(b0 + (tid >> 6)) * TT_ + t0 + (tid & 63)];
    if (t0 > 0 && tid < 128)
        hL[(t0 - 1) & 1][tid >> 6][tid & 63] =
            hcar[(size_t)(b0 + (tid >> 6)) * UU + j * 64 + (tid & 63)];
    __syncthreads();

    for (int tt = 0; tt < TC; ++tt) {
        const int s = t0 + tt;

        // xp for my collector slot (issued early; only sub==0 uses it)
        float xp = 0.f;
        if (sub == 0) xp = E2[stok[bc][tt] * UU + j * 64 + uc];

        // ---- produce partials(s) from h(s-1) + logits(s-1), fused k-loop ----
        if (s > 0) {
            const float4* h4p = (const float4*)hL[(s - 1) & 1][bp];
            float acc0 = 0.f, acc1 = 0.f, lsum = bdv;
            #pragma unroll
            for (int k4 = 0; k4 < 16; ++k4) {
                const float4 h4 = h4p[k4];
                const float hh[4] = {h4.x, h4.y, h4.z, h4.w};
                #pragma unroll
                for (int q = 0; q < 4; ++q) {
                    const int k = 4 * k4 + q;
                    acc0 = fmaf(hh[q], whp[k].x, acc0);
                    acc1 = fmaf(hh[q], whp[k].y, acc1);
                    lsum = fmaf(hh[q], wdreg[k], lsum);
                }
            }
            // push ASAP: (tag,val) pairs, sc0 copy + agent copy
            const u64 q0 = ((u64)(unsigned)s << 32) | __float_as_uint(acc0);
            const u64 q1 = ((u64)(unsigned)s << 32) | __float_as_uint(acc1);
            u64* d = pbuf + (((((size_t)(s & 1) * 32 + bg) * 8 + dstblk) * 8 + j) * 2 + bp) * 64
                          + (idx & 31) * 2;
            ((volatile u64*)d)[0] = q0;
            ((volatile u64*)d)[1] = q1;
            __hip_atomic_store(d,     q0, __ATOMIC_RELAXED, __HIP_MEMORY_SCOPE_AGENT);
            __hip_atomic_store(d + 1, q1, __ATOMIC_RELAXED, __HIP_MEMORY_SCOPE_AGENT);
            // logits(s-1) — off the critical path, after pushes
            if (s - 1 >= t0)
                atomicAdd(out + ((size_t)(b0 + bp) * TT_ + (s - 1)) * VV + idx, lsum);
        }

        // ---- collect h(s): poll my 2 srcs, alternate scopes ----
        float psum = 0.f;
        if (s > 0) {
            u64* base = pbuf + ((((size_t)(s & 1) * 32 + bg) * 8 + j) * 8) * 2 * 64;
            u64* a0 = base + (((2 * sub)     * 2 + bc) * 64 + uc);
            u64* a1 = base + (((2 * sub + 1) * 2 + bc) * 64 + uc);
            const unsigned want = (unsigned)s;
            u64 v0 = 0, v1 = 0;
            bool g0 = false, g1 = false;
            while (!(g0 && g1)) {
                if (!g0) { v0 = *(volatile u64*)a0; g0 = ((unsigned)(v0 >> 32) == want); }
                if (!g1) { v1 = *(volatile u64*)a1; g1 = ((unsigned)(v1 >> 32) == want); }
                if (g0 && g1) break;
                if (!g0) { v0 = __hip_atomic_load(a0, __ATOMIC_RELAXED, __HIP_MEMORY_SCOPE_AGENT);
                           g0 = ((unsigned)(v0 >> 32) == want); }
                if (!g1) { v1 = __hip_atomic_load(a1, __ATOMIC_RELAXED, __HIP_MEMORY_SCOPE_AGENT);
                           g1 = ((unsigned)(v1 >> 32) == want); }
            }
            psum = __uint_as_float((unsigned)v0) + __uint_as_float((unsigned)v1);
        }
        psum += __shfl_xor(psum, 1, 64);
        psum += __shfl_xor(psum, 2, 64);
        if (sub == 0)
            hL[s & 1][bc][uc] = tanh_fast(xp + psum);
        __syncthreads();
    }

    // ---- logits for the chunk's last step + h carry ----
    {
        const int sl = t0 + TC - 1;
        const float4* h4p = (const float4*)hL[sl & 1][bp];
        float lsum = bdv;
        #pragma unroll
        for (int k4 = 0; k4 < 16; ++k4) {
            const float4 h4 = h4p[k4];
            const float hh[4] = {h4.x, h4.y, h4.z, h4.w};
            #pragma unroll
            for (int q = 0; q < 4; ++q)
                lsum = fmaf(hh[q], wdreg[4 * k4 + q], lsum);
        }
        atomicAdd(out + ((size_t)(b0 + bp) * TT_ + sl) * VV + idx, lsum);
        if (tid < 128)
            hcar[(size_t)(b0 + (tid >> 6)) * UU + j * 64 + (tid & 63)] =
                hL[sl & 1][tid >> 6][tid & 63];
    }
}

extern "C" void kernel_launch(void* const* d_in, const int* in_sizes, int n_in,
                              void* d_out, int out_size, void* d_ws, size_t ws_size,
                              hipStream_t stream)
{
    (void)in_sizes; (void)n_in; (void)ws_size;

    const int*   toks = (const int*)  d_in[0];
    const float* emb  = (const float*)d_in[1];
    const float* Wx   = (const float*)d_in[2];
    const float* Wh   = (const float*)d_in[3];
    const float* bias = (const float*)d_in[4];
    const float* Wd   = (const float*)d_in[5];
    const float* bd   = (const float*)d_in[6];
    float* out = (float*)d_out;

    // ws layout: pbuf 4 MB u64 | hcar [BB*UU] f32 | E2 [EE*UU] f32
    u64*   pbuf = (u64*)d_ws;
    float* hcar = (float*)(pbuf + (size_t)2 * 32 * 8 * 8 * 2 * 64);
    float* E2   = hcar + (size_t)BB * UU;

    hipMemsetAsync(out, 0, (size_t)out_size * sizeof(float), stream);
    e2_kernel<<<EE, UU, 0, stream>>>(emb, Wx, bias, E2);

    for (int c = 0; c < TT_ / TC; ++c) {
        rnn_chunk_kernel<<<256, 512, 0, stream>>>(
            toks, E2, Wh, Wd, bd, pbuf, hcar, out, c * TC);
    }
}

// Round 6
// 3224.770 us; speedup vs baseline: 1.5244x; 1.5244x over previous
//
#include <hip/hip_runtime.h>
#include <math.h>

#define BB   64      // batch
#define TT_  1024    // sequence length
#define UU   512     // hidden units
#define VV   256     // vocab
#define EE   256     // embedding dim

typedef unsigned long long u64;

__device__ __forceinline__ float tanh_fast(float x) {
    // tanh(x) = 1 - 2/(e^{2x}+1); abs err ~1e-6 (validated: absmax 6e-5 end-to-end)
    float e = __expf(x + x);
    return 1.f - 2.f * __builtin_amdgcn_rcpf(e + 1.f);
}

// sc0-only loads: bypass L1, hit the XCD-shared L2 (fast path for same-XCD
// producer; stale-safe — agent fallback guarantees progress cross-XCD).
__device__ __forceinline__ void load2_sc0(const u64* p0, const u64* p1,
                                          u64& v0, u64& v1) {
    asm volatile("global_load_dwordx2 %0, %2, off sc0\n\t"
                 "global_load_dwordx2 %1, %3, off sc0\n\t"
                 "s_waitcnt vmcnt(0)"
                 : "=&v"(v0), "=&v"(v1)
                 : "v"(p0), "v"(p1)
                 : "memory");
}

// ---------------- E2 = emb @ Wx + b : [256, 512] ----------------
__global__ __launch_bounds__(512) void e2_kernel(
    const float* __restrict__ emb, const float* __restrict__ Wx,
    const float* __restrict__ bias, float* __restrict__ E2)
{
    const int v = blockIdx.x;
    const int u = threadIdx.x;
    float acc = bias[u];
    const float* er = emb + v * EE;
    #pragma unroll 8
    for (int e = 0; e < EE; ++e)
        acc = fmaf(er[e], Wx[e * UU + u], acc);
    E2[v * UU + u] = acc;
}

// ---------------- persistent fused recurrence + logits ----------------
// 256 blocks, 1/CU (LDS 149 KB): bg = bid&31 (2 batches), ug = bid>>5 (64 units).
// bid % 8 == bg % 8 -> the 8 ug-blocks of a bg co-locate on one XCD under
// round-robin dispatch (speed heuristic only; agent fallback = correctness).
// 512 thr = 8 waves; wave w = k-slice [64w,64w+64); lane: u4=lane&15, kq=lane>>4.
// h published twice: plain store (write-through to local L2) to hpubL +
// agent store (IF) to hpubG; consumers poll sc0 (L2) with agent fallback 1-in-4.
// Logits(s-1) done post-barrier: waves 2-7 overlap waves 0/1's tanh/publish tail.
__global__ __launch_bounds__(512, 2) void rnn_kernel(
    const int* __restrict__ toks, const float* __restrict__ E2,
    const float* __restrict__ Wh, const float* __restrict__ Wd,
    const float* __restrict__ bd,
    u64* hpubL, u64* hpubG,       // [2][BB][UU] (tag<<32|fp32) pairs
    float* out)
{
    __shared__ float WhLDS[UU * 64];          // 128 KB  [k][64u]
    __shared__ float hstage[8][2][64];        // 4 KB
    __shared__ float partials[2][8][2][64];   // 8 KB [ring][w][b][u]
    __shared__ float hL[2][2][64];            // 1 KB  [ring][b][u-local]
    __shared__ int   stok[2][TT_];            // 8 KB

    const int bid  = blockIdx.x;
    const int bg   = bid & 31;
    const int ug   = bid >> 5;
    const int tid  = threadIdx.x;
    const int w    = tid >> 6;
    const int lane = tid & 63;
    const int u4   = lane & 15;
    const int kq   = lane >> 4;
    const int b0   = bg * 2;

    // ---- Wh slice -> LDS (ONCE for all 1024 steps) ----
    const float4* Wh4  = (const float4*)Wh;   // [512][128]
    float4*       WhL4 = (float4*)WhLDS;      // [512][16]
    {
        const int col = tid & 15;
        const int kr0 = tid >> 4;
        #pragma unroll
        for (int p = 0; p < 16; ++p) {
            int k = p * 32 + kr0;
            WhL4[k * 16 + col] = Wh4[k * 128 + ug * 16 + col];
        }
    }
    // ---- tokens -> LDS ----
    for (int i = tid; i < 2 * TT_; i += 512)
        stok[i >> 10][i & (TT_ - 1)] = toks[(b0 + (i >> 10)) * TT_ + (i & (TT_ - 1))];

    // ---- Wd column -> VGPRs: thread owns (bmine, vmine) for logits ----
    const int bmine = w & 1;
    const int vmine = (w >> 1) * 64 + lane;
    float wdreg[64];
    #pragma unroll
    for (int u = 0; u < 64; ++u)
        wdreg[u] = Wd[(ug * 64 + u) * VV + vmine];
    const float bdv = (ug == 0) ? bd[vmine] : 0.f;

    __syncthreads();

    for (int s = 0; s < TT_; ++s) {
        float xp = 0.f;
        if (w < 2) xp = E2[stok[w][s] * UU + ug * 64 + lane];

        float acc0[4] = {0.f,0.f,0.f,0.f};
        float acc1[4] = {0.f,0.f,0.f,0.f};
        if (s > 0) {
            // ---- poll h(s-1) k-slice: sc0 local-L2 fast path, agent 1-in-4 ----
            const size_t off = ((size_t)((s - 1) & 1) * BB + b0) * UU + w * 64 + lane;
            const u64* aL0 = hpubL + off;  const u64* aL1 = aL0 + UU;
            const u64* aG0 = hpubG + off;  const u64* aG1 = aG0 + UU;
            const unsigned want = (unsigned)(s - 1);
            u64 p0 = 0, p1 = 0;
            bool g0 = false, g1 = false;
            int it = 0;
            while (true) {
                u64 t0v, t1v;
                load2_sc0(aL0, aL1, t0v, t1v);
                if (!g0 && (unsigned)(t0v >> 32) == want) { p0 = t0v; g0 = true; }
                if (!g1 && (unsigned)(t1v >> 32) == want) { p1 = t1v; g1 = true; }
                if ((__ballot(g0) & __ballot(g1)) == 0xFFFFFFFFFFFFFFFFull) break;
                if ((++it & 3) == 0) {
                    if (!g0) { u64 t = __hip_atomic_load(aG0, __ATOMIC_RELAXED, __HIP_MEMORY_SCOPE_AGENT);
                               if ((unsigned)(t >> 32) == want) { p0 = t; g0 = true; } }
                    if (!g1) { u64 t = __hip_atomic_load(aG1, __ATOMIC_RELAXED, __HIP_MEMORY_SCOPE_AGENT);
                               if ((unsigned)(t >> 32) == want) { p1 = t; g1 = true; } }
                    if ((__ballot(g0) & __ballot(g1)) == 0xFFFFFFFFFFFFFFFFull) break;
                }
            }
            // stage wave's k-slice (same-wave LDS write->read, no barrier)
            hstage[w][0][lane] = __uint_as_float((unsigned)p0);
            hstage[w][1][lane] = __uint_as_float((unsigned)p1);
            const float4* h40 = (const float4*)hstage[w][0];
            const float4* h41 = (const float4*)hstage[w][1];
            #pragma unroll
            for (int r = 0; r < 4; ++r) {
                float4 a = h40[kq * 4 + r];
                float4 c = h41[kq * 4 + r];
                float ha[4] = {a.x, a.y, a.z, a.w};
                float hc[4] = {c.x, c.y, c.z, c.w};
                #pragma unroll
                for (int q = 0; q < 4; ++q) {
                    float4 wv = WhL4[(w * 64 + kq * 16 + r * 4 + q) * 16 + u4];
                    acc0[0] = fmaf(ha[q], wv.x, acc0[0]);
                    acc0[1] = fmaf(ha[q], wv.y, acc0[1]);
                    acc0[2] = fmaf(ha[q], wv.z, acc0[2]);
                    acc0[3] = fmaf(ha[q], wv.w, acc0[3]);
                    acc1[0] = fmaf(hc[q], wv.x, acc1[0]);
                    acc1[1] = fmaf(hc[q], wv.y, acc1[1]);
                    acc1[2] = fmaf(hc[q], wv.z, acc1[2]);
                    acc1[3] = fmaf(hc[q], wv.w, acc1[3]);
                }
            }
        }

        // reduce over kq (lanes xor 16, 32)
        #pragma unroll
        for (int i = 0; i < 4; ++i) {
            acc0[i] += __shfl_xor(acc0[i], 16, 64);
            acc0[i] += __shfl_xor(acc0[i], 32, 64);
            acc1[i] += __shfl_xor(acc1[i], 16, 64);
            acc1[i] += __shfl_xor(acc1[i], 32, 64);
        }
        if (kq == 0) {
            *(float4*)&partials[s & 1][w][0][u4 * 4] =
                make_float4(acc0[0], acc0[1], acc0[2], acc0[3]);
            *(float4*)&partials[s & 1][w][1][u4 * 4] =
                make_float4(acc1[0], acc1[1], acc1[2], acc1[3]);
        }
        __syncthreads();

        // waves 0/1: finalize + publish ASAP (before their logits work)
        if (w < 2) {
            float ssum = xp;
            #pragma unroll
            for (int wv = 0; wv < 8; ++wv)
                ssum += partials[s & 1][wv][w][lane];
            float h = tanh_fast(ssum);
            hL[s & 1][w][lane] = h;
            const u64 pk = ((u64)(unsigned)s << 32) | __float_as_uint(h);
            const size_t po = ((size_t)(s & 1) * BB + (b0 + w)) * UU + ug * 64 + lane;
            __hip_atomic_store(hpubL + po, pk, __ATOMIC_RELAXED, __HIP_MEMORY_SCOPE_WORKGROUP);
            __hip_atomic_store(hpubG + po, pk, __ATOMIC_RELAXED, __HIP_MEMORY_SCOPE_AGENT);
        }

        // logits(s-1): reads hL[(s-1)&1], race-free via the barrier chain;
        // waves 2-7 do this while waves 0/1 run the tail above.
        if (s > 0) {
            const float4* hb = (const float4*)hL[(s - 1) & 1][bmine];
            float lsum = bdv;
            #pragma unroll
            for (int j = 0; j < 16; ++j) {
                float4 h4 = hb[j];
                lsum = fmaf(h4.x, wdreg[4*j+0], lsum);
                lsum = fmaf(h4.y, wdreg[4*j+1], lsum);
                lsum = fmaf(h4.z, wdreg[4*j+2], lsum);
                lsum = fmaf(h4.w, wdreg[4*j+3], lsum);
            }
            atomicAdd(out + ((size_t)(b0 + bmine) * TT_ + (s - 1)) * VV + vmine, lsum);
        }
    }

    // logits for the final step s = 1023 (hL valid; all waves past last barrier)
    __syncthreads();
    {
        const int s = TT_ - 1;
        const float4* hb = (const float4*)hL[s & 1][bmine];
        float lsum = bdv;
        #pragma unroll
        for (int j = 0; j < 16; ++j) {
            float4 h4 = hb[j];
            lsum = fmaf(h4.x, wdreg[4*j+0], lsum);
            lsum = fmaf(h4.y, wdreg[4*j+1], lsum);
            lsum = fmaf(h4.z, wdreg[4*j+2], lsum);
            lsum = fmaf(h4.w, wdreg[4*j+3], lsum);
        }
        atomicAdd(out + ((size_t)(b0 + bmine) * TT_ + s) * VV + vmine, lsum);
    }
}

extern "C" void kernel_launch(void* const* d_in, const int* in_sizes, int n_in,
                              void* d_out, int out_size, void* d_ws, size_t ws_size,
                              hipStream_t stream)
{
    (void)in_sizes; (void)n_in; (void)ws_size;

    const int*   toks = (const int*)  d_in[0];
    const float* emb  = (const float*)d_in[1];
    const float* Wx   = (const float*)d_in[2];
    const float* Wh   = (const float*)d_in[3];
    const float* bias = (const float*)d_in[4];
    const float* Wd   = (const float*)d_in[5];
    const float* bd   = (const float*)d_in[6];
    float* out = (float*)d_out;

    // ws: hpubL [2*BB*UU] u64 | hpubG [2*BB*UU] u64 | E2 [EE*UU] f32
    // poisoned 0xAA tags never match a step index -> no zeroing needed.
    u64*   hpubL = (u64*)d_ws;
    u64*   hpubG = hpubL + (size_t)2 * BB * UU;
    float* E2    = (float*)(hpubG + (size_t)2 * BB * UU);

    hipMemsetAsync(out, 0, (size_t)out_size * sizeof(float), stream);
    e2_kernel<<<EE, UU, 0, stream>>>(emb, Wx, bias, E2);
    rnn_kernel<<<256, 512, 0, stream>>>(toks, E2, Wh, Wd, bd, hpubL, hpubG, out);
}